// Round 12
// baseline (690.341 us; speedup 1.0000x reference)
//
#include <hip/hip_runtime.h>
#include <hip/hip_cooperative_groups.h>
#include <stdint.h>

namespace cg = cooperative_groups;

#define NB 8
#define NPTS 100000
#define NS 4096
#define NN 32
#define NCH 64
#define CLG 18
#define CELLS (1 << CLG)           // 64^3 dense voxel cells per batch
#define CMASK (CELLS - 1)
#define NBLK 512
#define NTHR 512
#define GSIZE (NBLK * NTHR)        // 262144 threads, 2 blocks/CU co-resident

// d_out float layout (element offsets)
#define OUT_MAIN 0ull                          // [8,4096,32,67]
#define OUT_SRC  70254592ull                   // [8,4096,32]
#define OUT_CTR  71303168ull                   // [8,4096]
#define OUT_CF   71335936ull                   // [8,100000]
#define OUT_SF   72135936ull                   // [8,100000]

typedef float f32x4 __attribute__((ext_vector_type(4)));

__host__ __device__ static inline uint32_t rotl32(uint32_t v, int d) {
    return (v << d) | (v >> (32 - d));
}

// JAX threefry2x32 (5 groups of 4 rounds), exact.
__host__ __device__ static inline void tf2x32(uint32_t k0, uint32_t k1,
                                              uint32_t x0, uint32_t x1,
                                              uint32_t& o0, uint32_t& o1) {
    uint32_t ks2 = k0 ^ k1 ^ 0x1BD11BDAu;
    x0 += k0; x1 += k1;
    x0 += x1; x1 = rotl32(x1, 13); x1 ^= x0;
    x0 += x1; x1 = rotl32(x1, 15); x1 ^= x0;
    x0 += x1; x1 = rotl32(x1, 26); x1 ^= x0;
    x0 += x1; x1 = rotl32(x1, 6);  x1 ^= x0;
    x0 += k1; x1 += ks2 + 1u;
    x0 += x1; x1 = rotl32(x1, 17); x1 ^= x0;
    x0 += x1; x1 = rotl32(x1, 29); x1 ^= x0;
    x0 += x1; x1 = rotl32(x1, 16); x1 ^= x0;
    x0 += x1; x1 = rotl32(x1, 24); x1 ^= x0;
    x0 += ks2; x1 += k0 + 2u;
    x0 += x1; x1 = rotl32(x1, 13); x1 ^= x0;
    x0 += x1; x1 = rotl32(x1, 15); x1 ^= x0;
    x0 += x1; x1 = rotl32(x1, 26); x1 ^= x0;
    x0 += x1; x1 = rotl32(x1, 6);  x1 ^= x0;
    x0 += k0; x1 += k1 + 3u;
    x0 += x1; x1 = rotl32(x1, 17); x1 ^= x0;
    x0 += x1; x1 = rotl32(x1, 29); x1 ^= x0;
    x0 += x1; x1 = rotl32(x1, 16); x1 ^= x0;
    x0 += x1; x1 = rotl32(x1, 24); x1 ^= x0;
    x0 += k1; x1 += ks2 + 4u;
    x0 += x1; x1 = rotl32(x1, 13); x1 ^= x0;
    x0 += x1; x1 = rotl32(x1, 15); x1 ^= x0;
    x0 += x1; x1 = rotl32(x1, 26); x1 ^= x0;
    x0 += x1; x1 = rotl32(x1, 6);  x1 ^= x0;
    x0 += ks2; x1 += k0 + 5u;
    o0 = x0; o1 = x1;
}

struct RngKeys {
    uint32_t c0[NB], c1[NB];   // partitionable k2 keys: centers
    uint32_t n0[NB], n1[NB];   // partitionable k2 keys: neighbor draws
};

// partitionable random_bits(key, 32, ...): element u -> o0^o1, counter (0,u)
__device__ static inline uint32_t pbits32(uint32_t k0, uint32_t k1, uint32_t u) {
    uint32_t o0, o1;
    tf2x32(k0, k1, 0u, u, o0, o1);
    return o0 ^ o1;
}

// dense cell index: x in low bits. Coords for N(0,1) data stay well inside [0,63].
__device__ static inline int cellidx(const float* __restrict__ p) {
    int vx = ((int)floorf(p[0] * 4.0f) + 32) & 63;
    int vy = ((int)floorf(p[1] * 4.0f) + 32) & 63;
    int vz = ((int)floorf(p[2] * 4.0f) + 32) & 63;
    return vx | (vy << 6) | (vz << 12);
}

struct Args {
    const float* pos; const float* feat; float* out;
    int* cnt; int* cursor; int* bctr; int* cidxOf;
    int* listA; int* listB; int* centers_ws; int* src_ws;
    RngKeys keys;
};

// =================== cooperative mega-kernel (2 blocks/CU) ===================
__global__ __launch_bounds__(NTHR, 4) void k_mega(Args a) {
    __shared__ int smem[4352];                 // 17408 B, reused per phase
    __shared__ int sbase;
    cg::grid_group grid = cg::this_grid();
    int tid = threadIdx.x, bid = blockIdx.x;
    int gt = bid * NTHR + tid;                 // 0 .. GSIZE-1

    // ---------- P0: zero counts + flag outputs + batch counters ----------
    for (int t = gt; t < (NB * CELLS) / 4; t += GSIZE)
        ((int4*)a.cnt)[t] = make_int4(0, 0, 0, 0);
    float* flags = a.out + OUT_CF;
    for (int t = gt; t < (2 * NB * NPTS) / 4; t += GSIZE)
        ((float4*)flags)[t] = make_float4(0.f, 0.f, 0.f, 0.f);
    if (gt < NB) a.bctr[gt] = 0;
    grid.sync();

    // ---------- P1: count points per cell (+ cache cell index) ----------
    for (int t = gt; t < NB * NPTS; t += GSIZE) {
        int b = t / NPTS;
        int cidx = cellidx(a.pos + (size_t)t * 3);
        a.cidxOf[t] = cidx;
        atomicAdd(&a.cnt[((size_t)b << CLG) + cidx], 1);
    }
    grid.sync();

    // ---------- P2: block-scan starts -> cursor (1 atomic per 2048 cells) ----
    for (int chunk = 0; chunk < 2; ++chunk) {
        int base_cell = (chunk * NBLK + bid) * 2048;     // 2048 cells per pass
        int b = base_cell >> CLG;                        // uniform per block
        int4 c4 = ((const int4*)a.cnt)[(base_cell >> 2) + tid];
        int s1 = c4.x + c4.y, s2 = s1 + c4.z, s3 = s2 + c4.w;
        smem[tid] = s3;
        __syncthreads();
        for (int off = 1; off < 512; off <<= 1) {        // Hillis-Steele inclusive
            int x = (tid >= off) ? smem[tid - off] : 0;
            __syncthreads();
            smem[tid] += x;
            __syncthreads();
        }
        int incl = smem[tid];
        if (tid == 511) sbase = atomicAdd(&a.bctr[b], smem[511]);
        __syncthreads();
        int base = sbase + incl - s3;                    // exclusive base of 4 cells
        int4 cur;
        cur.x = base;
        cur.y = base + c4.x;
        cur.z = base + s1;
        cur.w = base + s2;
        ((int4*)a.cursor)[(base_cell >> 2) + tid] = cur;
        __syncthreads();                                 // smem/sbase safe for next chunk
    }
    grid.sync();

    // ---------- P3: scatter arrival order (atomic returns position) ----------
    for (int t = gt; t < NB * NPTS; t += GSIZE) {
        int b = t / NPTS, i = t - b * NPTS;
        size_t gc = ((size_t)b << CLG) + a.cidxOf[t];
        int p = atomicAdd(&a.cursor[gc], 1);
        a.listA[(size_t)b * NPTS + p] = i;
    }
    grid.sync();

    // ---------- P4: rank within cell -> index-sorted lists ----------
    // After P3, cursor[gc] == start + cnt[gc].
    for (int t = gt; t < NB * NPTS; t += GSIZE) {
        int b = t / NPTS, i = t - b * NPTS;
        size_t gc = ((size_t)b << CLG) + a.cidxOf[t];
        int c = a.cnt[gc];
        int s0 = a.cursor[gc] - c;
        const int* L = a.listA + (size_t)b * NPTS + s0;
        int rank = 0;
        for (int k = 0; k < c; k++) rank += (L[k] < i) ? 1 : 0;
        a.listB[(size_t)b * NPTS + s0 + rank] = i;
    }
    grid.sync();

    // ---------- P5: centers + 27-bin lookup + cumsum + selection ----------
    {
        int (*scnt)[27] = (int(*)[27])smem;              // 16*27
        int (*slo)[27]  = (int(*)[27])(smem + 16 * 27);  // 16*27
        int g = tid >> 5, n = tid & 31;
        for (int it = 0; it < 4; ++it) {
            int bs = (it * NBLK + bid) * 16 + g;         // 0..32767
            int b = bs >> 12, s = bs & (NS - 1);
            uint32_t lower_c = pbits32(a.keys.c0[b], a.keys.c1[b], (uint32_t)s);
            int c = (int)(lower_c % 100000u);            // randint multiplier==0 path
            int ccell = a.cidxOf[(size_t)b * NPTS + c];
            __syncthreads();                             // protect LDS from prev iter
            if (n < 27) {
                int ncell = (ccell + (n / 9 - 1) + ((n / 3) % 3 - 1) * 64
                                   + (n % 3 - 1) * 4096) & CMASK;
                size_t gc = ((size_t)b << CLG) + ncell;
                int cc = a.cnt[gc];
                scnt[g][n] = cc;
                slo[g][n] = a.cursor[gc] - cc;           // start
            }
            if (n == 0) {
                a.centers_ws[bs] = c;
                a.out[OUT_CTR + bs] = (float)c;
                a.out[OUT_CF + (size_t)b * NPTS + c] = 1.0f;
            }
            __syncthreads();
            uint32_t lower = pbits32(a.keys.n0[b], a.keys.n1[b],
                                     (uint32_t)(s * NN + n));
            int total = 0;
            #pragma unroll
            for (int i = 0; i < 27; i++) total += scnt[g][i];
            int r = (int)(lower & 0x3FFFFFFFu) % total;  // span=2^30 multiplier==0
            int slot = 0, prev = 0, acc = 0;
            #pragma unroll
            for (int i = 0; i < 27; i++) {
                acc += scnt[g][i];
                if (r >= acc) { slot = i + 1; prev = acc; }
            }
            int pos_in = slo[g][slot] + (r - prev);
            int src = a.listB[(size_t)b * NPTS + pos_in];
            int oi = bs * NN + n;
            a.src_ws[oi] = src;
            a.out[OUT_SRC + oi] = (float)src;
            a.out[OUT_SF + (size_t)b * NPTS + src] = 1.0f;
        }
    }
    grid.sync();

    // ---------- P6: gather, 32 tiles of 64 rows per block ----------
    {
        float* sbuf = (float*)smem;                      // 64*67 floats = 17152 B
        for (int it = 0; it < 32; ++it) {
            long long tile = (long long)it * NBLK + bid;
            long long row0 = tile * 64;
            int g0 = tid >> 4, q0 = tid & 15;
            int g1 = g0 + 32;
            long long rowA = row0 + g0, rowB = row0 + g1;
            int bA = (int)(rowA >> 17), bB = (int)(rowB >> 17);
            int srcA = a.src_ws[rowA];
            int srcB = a.src_ws[rowB];
            const float4 fvA = *(const float4*)(a.feat + ((size_t)bA * NPTS + srcA) * NCH + 4 * q0);
            const float4 fvB = *(const float4*)(a.feat + ((size_t)bB * NPTS + srcB) * NCH + 4 * q0);
            __syncthreads();                             // prev iter LDS reads done
            float* sbA = sbuf + g0 * 67;
            sbA[3 + 4 * q0 + 0] = fvA.x;
            sbA[3 + 4 * q0 + 1] = fvA.y;
            sbA[3 + 4 * q0 + 2] = fvA.z;
            sbA[3 + 4 * q0 + 3] = fvA.w;
            float* sbB = sbuf + g1 * 67;
            sbB[3 + 4 * q0 + 0] = fvB.x;
            sbB[3 + 4 * q0 + 1] = fvB.y;
            sbB[3 + 4 * q0 + 2] = fvB.z;
            sbB[3 + 4 * q0 + 3] = fvB.w;
            if (tid < 192) {                             // rel: 3 floats x 64 rows
                int g = tid / 3, q = tid - g * 3;
                long long row = row0 + g;
                int b = (int)(row >> 17);
                int u = (int)(row & (NS * NN - 1));
                int s = u >> 5;
                int src = a.src_ws[row];
                int ctr = a.centers_ws[b * NS + s];
                sbuf[g * 67 + q] = a.pos[((size_t)b * NPTS + src) * 3 + q]
                                 - a.pos[((size_t)b * NPTS + ctr) * 3 + q];
            }
            __syncthreads();
            f32x4* ob = (f32x4*)(a.out + (size_t)row0 * 67);
            const f32x4* sv = (const f32x4*)sbuf;
            __builtin_nontemporal_store(sv[tid], &ob[tid]);
            __builtin_nontemporal_store(sv[tid + 512], &ob[tid + 512]);
            if (tid < 48) __builtin_nontemporal_store(sv[tid + 1024], &ob[tid + 1024]);
        }
    }
}

// =================== fallback: round-10 proven 7-kernel chain ===================
__global__ void k_zero(int* __restrict__ cnt, int* __restrict__ bctr,
                       float4* __restrict__ flags4) {
    int t = blockIdx.x * blockDim.x + threadIdx.x;   // exact: NB*CELLS
    cnt[t] = 0;
    if (t < (2 * NB * NPTS) / 4) flags4[t] = make_float4(0.f, 0.f, 0.f, 0.f);
    if (t < NB) bctr[t] = 0;
}

__global__ void k_count(const float* __restrict__ pos, int* __restrict__ cnt,
                        int* __restrict__ cidxOf) {
    int t = blockIdx.x * blockDim.x + threadIdx.x;   // exact: NB*NPTS
    int b = t / NPTS;
    int cidx = cellidx(pos + (size_t)t * 3);
    cidxOf[t] = cidx;
    atomicAdd(&cnt[((size_t)b << CLG) + cidx], 1);
}

__global__ void k_starts(const int* __restrict__ cnt, int* __restrict__ cursor,
                         int* __restrict__ bctr) {
    __shared__ int sdata[256];
    __shared__ int sbase;
    int t = blockIdx.x * blockDim.x + threadIdx.x;   // exact: NB*CELLS
    int tid = threadIdx.x;
    int b = t >> CLG;
    int c = cnt[t];
    sdata[tid] = c;
    __syncthreads();
    for (int off = 1; off < 256; off <<= 1) {
        int x = (tid >= off) ? sdata[tid - off] : 0;
        __syncthreads();
        sdata[tid] += x;
        __syncthreads();
    }
    if (tid == 255) sbase = atomicAdd(&bctr[b], sdata[255]);
    __syncthreads();
    cursor[t] = sbase + sdata[tid] - c;
}

__global__ void k_scatter(const int* __restrict__ cidxOf, int* __restrict__ cursor,
                          int* __restrict__ listA) {
    int t = blockIdx.x * blockDim.x + threadIdx.x;   // exact: NB*NPTS
    int b = t / NPTS, i = t - b * NPTS;
    size_t gc = ((size_t)b << CLG) + cidxOf[t];
    int a = atomicAdd(&cursor[gc], 1);
    listA[(size_t)b * NPTS + a] = i;
}

__global__ void k_rank(const int* __restrict__ cidxOf, const int* __restrict__ cnt,
                       const int* __restrict__ cursor,
                       const int* __restrict__ listA, int* __restrict__ listB) {
    int t = blockIdx.x * blockDim.x + threadIdx.x;   // exact: NB*NPTS
    int b = t / NPTS, i = t - b * NPTS;
    size_t gc = ((size_t)b << CLG) + cidxOf[t];
    int c = cnt[gc];
    int s0 = cursor[gc] - c;
    const int* L = listA + (size_t)b * NPTS + s0;
    int rank = 0;
    for (int k = 0; k < c; k++) rank += (L[k] < i) ? 1 : 0;
    listB[(size_t)b * NPTS + s0 + rank] = i;
}

__global__ void k_sel(RngKeys keys, const int* __restrict__ cidxOf,
                      const int* __restrict__ cnt, const int* __restrict__ cursor,
                      const int* __restrict__ listB,
                      int* __restrict__ centers_ws, int* __restrict__ src_ws,
                      float* __restrict__ out_ctr, float* __restrict__ out_cf,
                      float* __restrict__ out_src, float* __restrict__ out_sf) {
    __shared__ int scnt[8][27];
    __shared__ int slo[8][27];
    int tid = threadIdx.x;
    int g = tid >> 5, n = tid & 31;
    int bs = blockIdx.x * 8 + g;                     // exact: NB*NS/8 blocks
    int b = bs >> 12, s = bs & (NS - 1);
    uint32_t lower_c = pbits32(keys.c0[b], keys.c1[b], (uint32_t)s);
    int c = (int)(lower_c % 100000u);
    int ccell = cidxOf[(size_t)b * NPTS + c];
    if (n < 27) {
        int ncell = (ccell + (n / 9 - 1) + ((n / 3) % 3 - 1) * 64
                           + (n % 3 - 1) * 4096) & CMASK;
        size_t gc = ((size_t)b << CLG) + ncell;
        int cc = cnt[gc];
        scnt[g][n] = cc;
        slo[g][n] = cursor[gc] - cc;
    }
    if (n == 0) {
        centers_ws[bs] = c;
        out_ctr[bs] = (float)c;
        out_cf[(size_t)b * NPTS + c] = 1.0f;
    }
    __syncthreads();
    uint32_t lower = pbits32(keys.n0[b], keys.n1[b], (uint32_t)(s * NN + n));
    int total = 0;
    #pragma unroll
    for (int i = 0; i < 27; i++) total += scnt[g][i];
    int r = (int)(lower & 0x3FFFFFFFu) % total;
    int slot = 0, prev = 0, acc = 0;
    #pragma unroll
    for (int i = 0; i < 27; i++) {
        acc += scnt[g][i];
        if (r >= acc) { slot = i + 1; prev = acc; }
    }
    int pos_in = slo[g][slot] + (r - prev);
    int src = listB[(size_t)b * NPTS + pos_in];
    int oi = bs * NN + n;
    src_ws[oi] = src;
    out_src[oi] = (float)src;
    out_sf[(size_t)b * NPTS + src] = 1.0f;
}

__global__ void k_gather(const float* __restrict__ pos, const float* __restrict__ feat,
                         const int* __restrict__ centers_ws, const int* __restrict__ src_ws,
                         float* __restrict__ out) {
    __shared__ float sbuf[64 * 67];
    int t = threadIdx.x;                              // 512 threads
    long long row0 = (long long)blockIdx.x * 64;      // exact: NB*NS*NN rows
    int g0 = t >> 4,          q0 = t & 15;
    int g1 = (t + 512) >> 4,  q1 = t & 15;
    long long rowA = row0 + g0, rowB = row0 + g1;
    int bA = (int)(rowA >> 17), bB = (int)(rowB >> 17);
    int srcA = src_ws[rowA];
    int srcB = src_ws[rowB];
    const float4 fvA = *(const float4*)(feat + ((size_t)bA * NPTS + srcA) * NCH + 4 * q0);
    const float4 fvB = *(const float4*)(feat + ((size_t)bB * NPTS + srcB) * NCH + 4 * q1);
    float* sbA = sbuf + g0 * 67;
    sbA[3 + 4 * q0 + 0] = fvA.x;
    sbA[3 + 4 * q0 + 1] = fvA.y;
    sbA[3 + 4 * q0 + 2] = fvA.z;
    sbA[3 + 4 * q0 + 3] = fvA.w;
    float* sbB = sbuf + g1 * 67;
    sbB[3 + 4 * q1 + 0] = fvB.x;
    sbB[3 + 4 * q1 + 1] = fvB.y;
    sbB[3 + 4 * q1 + 2] = fvB.z;
    sbB[3 + 4 * q1 + 3] = fvB.w;
    if (t < 192) {
        int g = t / 3, q = t - g * 3;
        long long row = row0 + g;
        int b = (int)(row >> 17);
        int u = (int)(row & (NS * NN - 1));
        int s = u >> 5;
        int src = src_ws[row];
        int ctr = centers_ws[b * NS + s];
        sbuf[g * 67 + q] = pos[((size_t)b * NPTS + src) * 3 + q]
                         - pos[((size_t)b * NPTS + ctr) * 3 + q];
    }
    __syncthreads();
    f32x4* ob = (f32x4*)(out + (size_t)row0 * 67);
    const f32x4* sv = (const f32x4*)sbuf;
    __builtin_nontemporal_store(sv[t], &ob[t]);
    __builtin_nontemporal_store(sv[t + 512], &ob[t + 512]);
    if (t < 48) __builtin_nontemporal_store(sv[t + 1024], &ob[t + 1024]);
}

extern "C" void kernel_launch(void* const* d_in, const int* in_sizes, int n_in,
                              void* d_out, int out_size, void* d_ws, size_t ws_size,
                              hipStream_t stream) {
    (void)in_sizes; (void)n_in; (void)out_size; (void)ws_size;
    const float* pos = (const float*)d_in[0];
    const float* feat = (const float*)d_in[1];
    float* out = (float*)d_out;

    // ---- host-side JAX key-chain (threefry partitionable mode) ----
    RngKeys keys;
    for (int b = 0; b < NB; b++) {
        uint32_t rk0, rk1, kc0, kc1, kn0, kn1;
        tf2x32(0u, 42u, 0u, (uint32_t)b, rk0, rk1);
        tf2x32(rk0, rk1, 0u, 0u, kc0, kc1);
        tf2x32(rk0, rk1, 0u, 1u, kn0, kn1);
        tf2x32(kc0, kc1, 0u, 1u, keys.c0[b], keys.c1[b]);
        tf2x32(kn0, kn1, 0u, 1u, keys.n0[b], keys.n1[b]);
    }

    // ---- workspace layout (~30.4 MB) ----
    int* cnt        = (int*)d_ws;                      // NB*CELLS (16B aligned)
    int* cursor     = cnt + (size_t)NB * CELLS;        // NB*CELLS (16B aligned)
    int* bctr       = cursor + (size_t)NB * CELLS;     // NB
    int* cidxOf     = bctr + NB;                       // NB*NPTS
    int* listA      = cidxOf + (size_t)NB * NPTS;      // NB*NPTS
    int* listB      = listA + (size_t)NB * NPTS;       // NB*NPTS
    int* centers_ws = listB + (size_t)NB * NPTS;       // NB*NS
    int* src_ws     = centers_ws + (size_t)NB * NS;    // NB*NS*NN

    Args args;
    args.pos = pos; args.feat = feat; args.out = out;
    args.cnt = cnt; args.cursor = cursor; args.bctr = bctr; args.cidxOf = cidxOf;
    args.listA = listA; args.listB = listB;
    args.centers_ws = centers_ws; args.src_ws = src_ws;
    args.keys = keys;

    void* kparams[] = { &args };
    hipError_t err = hipLaunchCooperativeKernel((const void*)k_mega, dim3(NBLK),
                                                dim3(NTHR), kparams, 0, stream);
    if (err != hipSuccess) {
        // proven round-10 multi-kernel path
        k_zero   <<<(NB * CELLS) / 256, 256, 0, stream>>>(cnt, bctr,
                                                          (float4*)(out + OUT_CF));
        k_count  <<<(NB * NPTS) / 256, 256, 0, stream>>>(pos, cnt, cidxOf);
        k_starts <<<(NB * CELLS) / 256, 256, 0, stream>>>(cnt, cursor, bctr);
        k_scatter<<<(NB * NPTS) / 256, 256, 0, stream>>>(cidxOf, cursor, listA);
        k_rank   <<<(NB * NPTS) / 256, 256, 0, stream>>>(cidxOf, cnt, cursor, listA, listB);
        k_sel    <<<(NB * NS) / 8, 256, 0, stream>>>(keys, cidxOf, cnt, cursor, listB,
                                                     centers_ws, src_ws,
                                                     out + OUT_CTR, out + OUT_CF,
                                                     out + OUT_SRC, out + OUT_SF);
        k_gather <<<(NB * NS * NN) / 64, 512, 0, stream>>>(pos, feat, centers_ws,
                                                           src_ws, out);
    }
}

// Round 13
// 378.380 us; speedup vs baseline: 1.8245x; 1.8245x over previous
//
#include <hip/hip_runtime.h>
#include <stdint.h>

#define NB 8
#define NPTS 100000
#define NS 4096
#define NN 32
#define NCH 64
#define CLG 18
#define CELLS (1 << CLG)           // 64^3 dense voxel cells per batch
#define CMASK (CELLS - 1)

// d_out float layout (element offsets)
#define OUT_MAIN 0ull                          // [8,4096,32,67]
#define OUT_SRC  70254592ull                   // [8,4096,32]
#define OUT_CTR  71303168ull                   // [8,4096]
#define OUT_CF   71335936ull                   // [8,100000]
#define OUT_SF   72135936ull                   // [8,100000]

typedef float f32x4 __attribute__((ext_vector_type(4)));

__host__ __device__ static inline uint32_t rotl32(uint32_t v, int d) {
    return (v << d) | (v >> (32 - d));
}

// JAX threefry2x32 (5 groups of 4 rounds), exact.
__host__ __device__ static inline void tf2x32(uint32_t k0, uint32_t k1,
                                              uint32_t x0, uint32_t x1,
                                              uint32_t& o0, uint32_t& o1) {
    uint32_t ks2 = k0 ^ k1 ^ 0x1BD11BDAu;
    x0 += k0; x1 += k1;
    x0 += x1; x1 = rotl32(x1, 13); x1 ^= x0;
    x0 += x1; x1 = rotl32(x1, 15); x1 ^= x0;
    x0 += x1; x1 = rotl32(x1, 26); x1 ^= x0;
    x0 += x1; x1 = rotl32(x1, 6);  x1 ^= x0;
    x0 += k1; x1 += ks2 + 1u;
    x0 += x1; x1 = rotl32(x1, 17); x1 ^= x0;
    x0 += x1; x1 = rotl32(x1, 29); x1 ^= x0;
    x0 += x1; x1 = rotl32(x1, 16); x1 ^= x0;
    x0 += x1; x1 = rotl32(x1, 24); x1 ^= x0;
    x0 += ks2; x1 += k0 + 2u;
    x0 += x1; x1 = rotl32(x1, 13); x1 ^= x0;
    x0 += x1; x1 = rotl32(x1, 15); x1 ^= x0;
    x0 += x1; x1 = rotl32(x1, 26); x1 ^= x0;
    x0 += x1; x1 = rotl32(x1, 6);  x1 ^= x0;
    x0 += k0; x1 += k1 + 3u;
    x0 += x1; x1 = rotl32(x1, 17); x1 ^= x0;
    x0 += x1; x1 = rotl32(x1, 29); x1 ^= x0;
    x0 += x1; x1 = rotl32(x1, 16); x1 ^= x0;
    x0 += x1; x1 = rotl32(x1, 24); x1 ^= x0;
    x0 += k1; x1 += ks2 + 4u;
    x0 += x1; x1 = rotl32(x1, 13); x1 ^= x0;
    x0 += x1; x1 = rotl32(x1, 15); x1 ^= x0;
    x0 += x1; x1 = rotl32(x1, 26); x1 ^= x0;
    x0 += x1; x1 = rotl32(x1, 6);  x1 ^= x0;
    x0 += ks2; x1 += k0 + 5u;
    o0 = x0; o1 = x1;
}

struct RngKeys {
    uint32_t c0[NB], c1[NB];   // partitionable k2 keys: centers
    uint32_t n0[NB], n1[NB];   // partitionable k2 keys: neighbor draws
};

// partitionable random_bits(key, 32, ...): element u -> o0^o1, counter (0,u)
__device__ static inline uint32_t pbits32(uint32_t k0, uint32_t k1, uint32_t u) {
    uint32_t o0, o1;
    tf2x32(k0, k1, 0u, u, o0, o1);
    return o0 ^ o1;
}

// dense cell index: x in low bits. Coords for N(0,1) data stay well inside [0,63].
__device__ static inline int cellidx(const float* __restrict__ p) {
    int vx = ((int)floorf(p[0] * 4.0f) + 32) & 63;
    int vy = ((int)floorf(p[1] * 4.0f) + 32) & 63;
    int vz = ((int)floorf(p[2] * 4.0f) + 32) & 63;
    return vx | (vy << 6) | (vz << 12);
}

// ---------------- P0: init counts + flag outputs (vectorized) -----------------
__global__ void k_zero(int4* __restrict__ cnt4, int* __restrict__ bctr,
                       float4* __restrict__ flags4) {
    int t = blockIdx.x * blockDim.x + threadIdx.x;   // exact: NB*CELLS/4
    cnt4[t] = make_int4(0, 0, 0, 0);
    if (t < (2 * NB * NPTS) / 4) flags4[t] = make_float4(0.f, 0.f, 0.f, 0.f);
    if (t < NB) bctr[t] = 0;
}

// ---------------- P1: count points per cell (+ cache cell index) -----------
__global__ void k_count(const float* __restrict__ pos, int* __restrict__ cnt,
                        int* __restrict__ cidxOf) {
    int t = blockIdx.x * blockDim.x + threadIdx.x;   // exact: NB*NPTS
    int b = t / NPTS;
    int cidx = cellidx(pos + (size_t)t * 3);
    cidxOf[t] = cidx;
    atomicAdd(&cnt[((size_t)b << CLG) + cidx], 1);
}

// ------ P2: write cursors = cell start (block scan, 1 atomic/block) --------
__global__ void k_starts(const int* __restrict__ cnt, int* __restrict__ cursor,
                         int* __restrict__ bctr) {
    __shared__ int sdata[256];
    __shared__ int sbase;
    int t = blockIdx.x * blockDim.x + threadIdx.x;   // exact: NB*CELLS
    int tid = threadIdx.x;
    int b = t >> CLG;                                // uniform per block
    int c = cnt[t];
    sdata[tid] = c;
    __syncthreads();
    for (int off = 1; off < 256; off <<= 1) {        // Hillis-Steele inclusive
        int x = (tid >= off) ? sdata[tid - off] : 0;
        __syncthreads();
        sdata[tid] += x;
        __syncthreads();
    }
    if (tid == 255) sbase = atomicAdd(&bctr[b], sdata[255]);
    __syncthreads();
    cursor[t] = sbase + sdata[tid] - c;              // exclusive prefix (start)
}

// ------ P3: scatter arrival order (single atomic, no contended reads) ------
__global__ void k_scatter(const int* __restrict__ cidxOf, int* __restrict__ cursor,
                          int* __restrict__ listA) {
    int t = blockIdx.x * blockDim.x + threadIdx.x;   // exact: NB*NPTS
    int b = t / NPTS, i = t - b * NPTS;
    size_t gc = ((size_t)b << CLG) + cidxOf[t];
    int a = atomicAdd(&cursor[gc], 1);               // returns absolute position
    listA[(size_t)b * NPTS + a] = i;
}

// ---------------- P4: rank within cell -> index-sorted lists ------------
// After scatter, cursor[gc] == start + cnt[gc].
__global__ void k_rank(const int* __restrict__ cidxOf, const int* __restrict__ cnt,
                       const int* __restrict__ cursor,
                       const int* __restrict__ listA, int* __restrict__ listB) {
    int t = blockIdx.x * blockDim.x + threadIdx.x;   // exact: NB*NPTS
    int b = t / NPTS, i = t - b * NPTS;
    size_t gc = ((size_t)b << CLG) + cidxOf[t];
    int c = cnt[gc];
    int s0 = cursor[gc] - c;                         // start
    const int* L = listA + (size_t)b * NPTS + s0;
    int rank = 0;
    for (int k = 0; k < c; k++) rank += (L[k] < i) ? 1 : 0;
    listB[(size_t)b * NPTS + s0 + rank] = i;
}

// ------- P5: selection + gather fused. 256 threads = 8 samples = 256 rows. --
// Block's rows are globally contiguous: row = blockIdx.x*256 + tid.
__global__ __launch_bounds__(256) void k_selgather(
        RngKeys keys, const float* __restrict__ pos, const float* __restrict__ feat,
        const int* __restrict__ cidxOf, const int* __restrict__ cnt,
        const int* __restrict__ cursor, const int* __restrict__ listB,
        float* __restrict__ out) {
    __shared__ int scnt[8][27];
    __shared__ int slo[8][27];
    __shared__ int ssrc[256];
    __shared__ float sctr[8][3];
    __shared__ float sbuf[64 * 67];                  // 17152 B tile buffer
    int tid = threadIdx.x;
    int g = tid >> 5, n = tid & 31;
    int bs = blockIdx.x * 8 + g;                     // exact: NB*NS/8 blocks
    int b = bs >> 12, s = bs & (NS - 1);             // b uniform/block (512 blk/batch)
    // ---- selection (identical arithmetic to proven k_sel) ----
    uint32_t lower_c = pbits32(keys.c0[b], keys.c1[b], (uint32_t)s);
    int c = (int)(lower_c % 100000u);                // randint multiplier==0 path
    int ccell = cidxOf[(size_t)b * NPTS + c];
    if (n < 27) {
        int ncell = (ccell + (n / 9 - 1) + ((n / 3) % 3 - 1) * 64
                           + (n % 3 - 1) * 4096) & CMASK;
        size_t gc = ((size_t)b << CLG) + ncell;
        int cc = cnt[gc];
        scnt[g][n] = cc;
        slo[g][n] = cursor[gc] - cc;                 // start
    }
    if (n < 3) sctr[g][n] = pos[((size_t)b * NPTS + c) * 3 + n];
    if (n == 0) {
        out[OUT_CTR + bs] = (float)c;
        out[OUT_CF + (size_t)b * NPTS + c] = 1.0f;
    }
    __syncthreads();
    uint32_t lower = pbits32(keys.n0[b], keys.n1[b], (uint32_t)(s * NN + n));
    int total = 0;
    #pragma unroll
    for (int i = 0; i < 27; i++) total += scnt[g][i];
    int r = (int)(lower & 0x3FFFFFFFu) % total;      // span=2^30 -> multiplier==0 path
    int slot = 0, prev = 0, acc = 0;
    #pragma unroll
    for (int i = 0; i < 27; i++) {
        acc += scnt[g][i];
        if (r >= acc) { slot = i + 1; prev = acc; }
    }
    int pos_in = slo[g][slot] + (r - prev);
    int src = listB[(size_t)b * NPTS + pos_in];
    ssrc[tid] = src;
    out[OUT_SRC + (size_t)bs * NN + n] = (float)src;
    out[OUT_SF + (size_t)b * NPTS + src] = 1.0f;
    // ---- gather: 4 tiles of 64 rows; 4 threads/row, 4 float4 loads in flight --
    size_t outbase = (size_t)blockIdx.x * 256 * 67;
    for (int j = 0; j < 4; ++j) {
        __syncthreads();                             // ssrc ready / prev tile reads done
        int rloc = tid >> 2, q = tid & 3;
        int src_r = ssrc[j * 64 + rloc];
        const float* f = feat + ((size_t)b * NPTS + src_r) * NCH + q * 16;
        float4 f0 = *(const float4*)(f + 0);
        float4 f1 = *(const float4*)(f + 4);
        float4 f2 = *(const float4*)(f + 8);
        float4 f3 = *(const float4*)(f + 12);
        float* sb = sbuf + rloc * 67 + 3 + q * 16;
        sb[0] = f0.x;  sb[1] = f0.y;  sb[2] = f0.z;  sb[3] = f0.w;
        sb[4] = f1.x;  sb[5] = f1.y;  sb[6] = f1.z;  sb[7] = f1.w;
        sb[8] = f2.x;  sb[9] = f2.y;  sb[10] = f2.z; sb[11] = f2.w;
        sb[12] = f3.x; sb[13] = f3.y; sb[14] = f3.z; sb[15] = f3.w;
        if (tid < 192) {                             // rel: 3 floats x 64 rows
            int gr = tid / 3, qq = tid - gr * 3;
            int R2 = j * 64 + gr;
            int s2 = ssrc[R2];
            sbuf[gr * 67 + qq] = pos[((size_t)b * NPTS + s2) * 3 + qq]
                               - sctr[R2 >> 5][qq];
        }
        __syncthreads();
        // 64*67 = 4288 floats = 1072 f32x4, contiguous & 16B-aligned.
        // write-once output -> nontemporal (keep L2/L3 for feat)
        f32x4* ob = (f32x4*)(out + outbase + (size_t)j * 64 * 67);
        const f32x4* sv = (const f32x4*)sbuf;
        __builtin_nontemporal_store(sv[tid], &ob[tid]);
        __builtin_nontemporal_store(sv[tid + 256], &ob[tid + 256]);
        __builtin_nontemporal_store(sv[tid + 512], &ob[tid + 512]);
        __builtin_nontemporal_store(sv[tid + 768], &ob[tid + 768]);
        if (tid < 48) __builtin_nontemporal_store(sv[tid + 1024], &ob[tid + 1024]);
    }
}

extern "C" void kernel_launch(void* const* d_in, const int* in_sizes, int n_in,
                              void* d_out, int out_size, void* d_ws, size_t ws_size,
                              hipStream_t stream) {
    (void)in_sizes; (void)n_in; (void)out_size; (void)ws_size;
    const float* pos = (const float*)d_in[0];
    const float* feat = (const float*)d_in[1];
    float* out = (float*)d_out;

    // ---- host-side JAX key-chain (threefry partitionable mode) ----
    RngKeys keys;
    for (int b = 0; b < NB; b++) {
        uint32_t rk0, rk1, kc0, kc1, kn0, kn1;
        tf2x32(0u, 42u, 0u, (uint32_t)b, rk0, rk1);
        tf2x32(rk0, rk1, 0u, 0u, kc0, kc1);
        tf2x32(rk0, rk1, 0u, 1u, kn0, kn1);
        tf2x32(kc0, kc1, 0u, 1u, keys.c0[b], keys.c1[b]);
        tf2x32(kn0, kn1, 0u, 1u, keys.n0[b], keys.n1[b]);
    }

    // ---- workspace layout (~22 MB) ----
    int* cnt        = (int*)d_ws;                      // NB*CELLS (16B aligned)
    int* cursor     = cnt + (size_t)NB * CELLS;        // NB*CELLS
    int* bctr       = cursor + (size_t)NB * CELLS;     // NB
    int* cidxOf     = bctr + NB;                       // NB*NPTS
    int* listA      = cidxOf + (size_t)NB * NPTS;      // NB*NPTS
    int* listB      = listA + (size_t)NB * NPTS;       // NB*NPTS

    k_zero     <<<(NB * CELLS / 4) / 256, 256, 0, stream>>>((int4*)cnt, bctr,
                                                            (float4*)(out + OUT_CF));
    k_count    <<<(NB * NPTS) / 256, 256, 0, stream>>>(pos, cnt, cidxOf);
    k_starts   <<<(NB * CELLS) / 256, 256, 0, stream>>>(cnt, cursor, bctr);
    k_scatter  <<<(NB * NPTS) / 256, 256, 0, stream>>>(cidxOf, cursor, listA);
    k_rank     <<<(NB * NPTS) / 256, 256, 0, stream>>>(cidxOf, cnt, cursor, listA, listB);
    k_selgather<<<(NB * NS) / 8, 256, 0, stream>>>(keys, pos, feat, cidxOf, cnt,
                                                   cursor, listB, out);
}

// Round 14
// 369.304 us; speedup vs baseline: 1.8693x; 1.0246x over previous
//
#include <hip/hip_runtime.h>
#include <stdint.h>

#define NB 8
#define NPTS 100000
#define NS 4096
#define NN 32
#define NCH 64
#define TLG 17
#define TSLOTS (1 << TLG)          // 131072 hash slots per batch (load ~0.34)
#define TMASK (TSLOTS - 1)

// d_out float layout (element offsets)
#define OUT_MAIN 0ull                          // [8,4096,32,67]
#define OUT_SRC  70254592ull                   // [8,4096,32]
#define OUT_CTR  71303168ull                   // [8,4096]
#define OUT_CF   71335936ull                   // [8,100000]
#define OUT_SF   72135936ull                   // [8,100000]

typedef float f32x4 __attribute__((ext_vector_type(4)));

__host__ __device__ static inline uint32_t rotl32(uint32_t v, int d) {
    return (v << d) | (v >> (32 - d));
}

// JAX threefry2x32 (5 groups of 4 rounds), exact.
__host__ __device__ static inline void tf2x32(uint32_t k0, uint32_t k1,
                                              uint32_t x0, uint32_t x1,
                                              uint32_t& o0, uint32_t& o1) {
    uint32_t ks2 = k0 ^ k1 ^ 0x1BD11BDAu;
    x0 += k0; x1 += k1;
    x0 += x1; x1 = rotl32(x1, 13); x1 ^= x0;
    x0 += x1; x1 = rotl32(x1, 15); x1 ^= x0;
    x0 += x1; x1 = rotl32(x1, 26); x1 ^= x0;
    x0 += x1; x1 = rotl32(x1, 6);  x1 ^= x0;
    x0 += k1; x1 += ks2 + 1u;
    x0 += x1; x1 = rotl32(x1, 17); x1 ^= x0;
    x0 += x1; x1 = rotl32(x1, 29); x1 ^= x0;
    x0 += x1; x1 = rotl32(x1, 16); x1 ^= x0;
    x0 += x1; x1 = rotl32(x1, 24); x1 ^= x0;
    x0 += ks2; x1 += k0 + 2u;
    x0 += x1; x1 = rotl32(x1, 13); x1 ^= x0;
    x0 += x1; x1 = rotl32(x1, 15); x1 ^= x0;
    x0 += x1; x1 = rotl32(x1, 26); x1 ^= x0;
    x0 += x1; x1 = rotl32(x1, 6);  x1 ^= x0;
    x0 += k0; x1 += k1 + 3u;
    x0 += x1; x1 = rotl32(x1, 17); x1 ^= x0;
    x0 += x1; x1 = rotl32(x1, 29); x1 ^= x0;
    x0 += x1; x1 = rotl32(x1, 16); x1 ^= x0;
    x0 += x1; x1 = rotl32(x1, 24); x1 ^= x0;
    x0 += k1; x1 += ks2 + 4u;
    x0 += x1; x1 = rotl32(x1, 13); x1 ^= x0;
    x0 += x1; x1 = rotl32(x1, 15); x1 ^= x0;
    x0 += x1; x1 = rotl32(x1, 26); x1 ^= x0;
    x0 += x1; x1 = rotl32(x1, 6);  x1 ^= x0;
    x0 += ks2; x1 += k0 + 5u;
    o0 = x0; o1 = x1;
}

struct RngKeys {
    uint32_t c0[NB], c1[NB];   // partitionable k2 keys: centers
    uint32_t n0[NB], n1[NB];   // partitionable k2 keys: neighbor draws
};

// partitionable random_bits(key, 32, ...): element u -> o0^o1, counter (0,u)
__device__ static inline uint32_t pbits32(uint32_t k0, uint32_t k1, uint32_t u) {
    uint32_t o0, o1;
    tf2x32(k0, k1, 0u, u, o0, o1);
    return o0 ^ o1;
}

// packed voxel key == reference hash: (vx+512)<<20 | (vy+512)<<10 | (vz+512)
__device__ static inline int voxhash(const float* __restrict__ p) {
    int vx = (int)floorf(p[0] * 4.0f);
    int vy = (int)floorf(p[1] * 4.0f);
    int vz = (int)floorf(p[2] * 4.0f);
    return ((vx + 512) << 20) | ((vy + 512) << 10) | (vz + 512);
}

__device__ static inline int hslot(int hk) {
    return (int)(((uint32_t)hk * 2654435761u) >> (32 - TLG)) & TMASK;
}

// ---------------- P0: init tables + flag outputs (vectorized) ---------------
__global__ void k_zero(int4* __restrict__ key4, int4* __restrict__ cnt4,
                       int* __restrict__ bctr, float4* __restrict__ flags4) {
    int t = blockIdx.x * blockDim.x + threadIdx.x;   // exact: NB*TSLOTS/4 = 262144
    key4[t] = make_int4(-1, -1, -1, -1);
    cnt4[t] = make_int4(0, 0, 0, 0);
    for (int u = t; u < (2 * NB * NPTS) / 4; u += (NB * TSLOTS) / 4)
        flags4[u] = make_float4(0.f, 0.f, 0.f, 0.f);
    if (t < NB) bctr[t] = 0;
}

// -------- P1: insert + count, CAS fast-path (+ remember slot per point) -----
__global__ void k_insert(const float* __restrict__ pos,
                         int* __restrict__ tab_key, int* __restrict__ cnt,
                         int* __restrict__ slotOf) {
    int t = blockIdx.x * blockDim.x + threadIdx.x;   // exact: NB*NPTS
    int b = t / NPTS;
    int hk = voxhash(pos + (size_t)t * 3);
    int base = b << TLG;
    int slot = hslot(hk);
    while (true) {
        int k = tab_key[base + slot];                // plain load first (L2-hot)
        if (k == hk) break;                          // common case: key present
        if (k == -1) {
            int prev = atomicCAS(&tab_key[base + slot], -1, hk);
            if (prev == -1 || prev == hk) break;
            // lost race to a different key: fall through, advance
        }
        slot = (slot + 1) & TMASK;
    }
    slotOf[t] = slot;
    atomicAdd(&cnt[base + slot], 1);
}

// ------ P2: write cursors = bucket start (block scan, 1 atomic/block) -------
// cnt[] stays intact; cursor[] becomes the fill cursor.
__global__ void k_starts(const int* __restrict__ cnt, int* __restrict__ cursor,
                         int* __restrict__ bctr) {
    __shared__ int sdata[256];
    __shared__ int sbase;
    int t = blockIdx.x * blockDim.x + threadIdx.x;   // exact: NB*TSLOTS
    int tid = threadIdx.x;
    int b = t >> TLG;                                // uniform per block
    int c = cnt[t];
    sdata[tid] = c;
    __syncthreads();
    for (int off = 1; off < 256; off <<= 1) {        // Hillis-Steele inclusive
        int x = (tid >= off) ? sdata[tid - off] : 0;
        __syncthreads();
        sdata[tid] += x;
        __syncthreads();
    }
    if (tid == 255) sbase = atomicAdd(&bctr[b], sdata[255]);
    __syncthreads();
    cursor[t] = sbase + sdata[tid] - c;              // exclusive prefix (start)
}

// ------ P3: scatter arrival order (single atomic, position = return) --------
__global__ void k_scatter(const int* __restrict__ slotOf, int* __restrict__ cursor,
                          int* __restrict__ listA) {
    int t = blockIdx.x * blockDim.x + threadIdx.x;   // exact: NB*NPTS
    int b = t / NPTS, i = t - b * NPTS;
    int gc = (b << TLG) + slotOf[t];
    int p = atomicAdd(&cursor[gc], 1);               // returns absolute position
    listA[(size_t)b * NPTS + p] = i;
}

// ---------------- P4: rank within bucket -> index-sorted lists --------------
// After scatter, cursor[gc] == start + cnt[gc].
__global__ void k_rank(const int* __restrict__ slotOf, const int* __restrict__ cnt,
                       const int* __restrict__ cursor,
                       const int* __restrict__ listA, int* __restrict__ listB) {
    int t = blockIdx.x * blockDim.x + threadIdx.x;   // exact: NB*NPTS
    int b = t / NPTS, i = t - b * NPTS;
    int gc = (b << TLG) + slotOf[t];
    int c = cnt[gc];
    int s0 = cursor[gc] - c;                         // start
    const int* L = listA + (size_t)b * NPTS + s0;
    int rank = 0;
    for (int k = 0; k < c; k++) rank += (L[k] < i) ? 1 : 0;
    listB[(size_t)b * NPTS + s0 + rank] = i;
}

// ------- P5: centers + 27-bin lookup + cumsum + selection (fused) -----------
__global__ void k_sel(RngKeys keys, const int* __restrict__ slotOf,
                      const int* __restrict__ tab_key, const int* __restrict__ cnt,
                      const int* __restrict__ cursor, const int* __restrict__ listB,
                      int* __restrict__ centers_ws, int* __restrict__ src_ws,
                      float* __restrict__ out_ctr, float* __restrict__ out_cf,
                      float* __restrict__ out_src, float* __restrict__ out_sf) {
    __shared__ int scnt[8][27];
    __shared__ int slo[8][27];
    int tid = threadIdx.x;                           // 256 threads = 8 samples
    int g = tid >> 5, n = tid & 31;
    int bs = blockIdx.x * 8 + g;                     // exact: NB*NS/8 blocks
    int b = bs >> 12, s = bs & (NS - 1);
    uint32_t lower_c = pbits32(keys.c0[b], keys.c1[b], (uint32_t)s);
    int c = (int)(lower_c % 100000u);                // randint multiplier==0 path
    int base = b << TLG;
    // center's packed voxel key via its slot (4+4 B, both L2-hot)
    int chk = tab_key[base + slotOf[(size_t)b * NPTS + c]];
    if (n < 27) {
        // neighbor voxel key by integer offset (coords never at the ±512 edge)
        int hk = chk + ((n / 9) - 1) * (1 << 20)
                     + (((n / 3) % 3) - 1) * (1 << 10)
                     + ((n % 3) - 1);
        int slot = hslot(hk);
        int lo = 0, cc = 0;
        while (true) {
            int k = tab_key[base + slot];
            if (k == hk) { cc = cnt[base + slot]; lo = cursor[base + slot] - cc; break; }
            if (k == -1) break;
            slot = (slot + 1) & TMASK;
        }
        scnt[g][n] = cc;
        slo[g][n] = lo;
    }
    if (n == 0) {
        centers_ws[bs] = c;
        out_ctr[bs] = (float)c;
        out_cf[(size_t)b * NPTS + c] = 1.0f;
    }
    __syncthreads();
    uint32_t lower = pbits32(keys.n0[b], keys.n1[b], (uint32_t)(s * NN + n));
    int total = 0;
    #pragma unroll
    for (int i = 0; i < 27; i++) total += scnt[g][i];
    int r = (int)(lower & 0x3FFFFFFFu) % total;      // span=2^30 -> multiplier==0 path
    int slot = 0, prev = 0, acc = 0;
    #pragma unroll
    for (int i = 0; i < 27; i++) {
        acc += scnt[g][i];
        if (r >= acc) { slot = i + 1; prev = acc; }
    }
    int pos_in = slo[g][slot] + (r - prev);
    int src = listB[(size_t)b * NPTS + pos_in];
    int oi = bs * NN + n;
    src_ws[oi] = src;
    out_src[oi] = (float)src;
    out_sf[(size_t)b * NPTS + src] = 1.0f;
}

// ---- P6: output gather: 64 rows/block, 2 independent feat loads/thread -----
__global__ void k_gather(const float* __restrict__ pos, const float* __restrict__ feat,
                         const int* __restrict__ centers_ws, const int* __restrict__ src_ws,
                         float* __restrict__ out) {
    __shared__ float sbuf[64 * 67];                   // 17152 B
    int t = threadIdx.x;                              // 512 threads
    long long row0 = (long long)blockIdx.x * 64;      // exact: NB*NS*NN rows
    // two feat-quarter slots per thread -> 2 loads in flight (MLP)
    int g0 = t >> 4, q0 = t & 15;
    int g1 = g0 + 32;
    long long rowA = row0 + g0, rowB = row0 + g1;
    int bA = (int)(rowA >> 17), bB = (int)(rowB >> 17);
    int srcA = src_ws[rowA];
    int srcB = src_ws[rowB];
    const float4 fvA = *(const float4*)(feat + ((size_t)bA * NPTS + srcA) * NCH + 4 * q0);
    const float4 fvB = *(const float4*)(feat + ((size_t)bB * NPTS + srcB) * NCH + 4 * q0);
    float* sbA = sbuf + g0 * 67;
    sbA[3 + 4 * q0 + 0] = fvA.x;
    sbA[3 + 4 * q0 + 1] = fvA.y;
    sbA[3 + 4 * q0 + 2] = fvA.z;
    sbA[3 + 4 * q0 + 3] = fvA.w;
    float* sbB = sbuf + g1 * 67;
    sbB[3 + 4 * q0 + 0] = fvB.x;
    sbB[3 + 4 * q0 + 1] = fvB.y;
    sbB[3 + 4 * q0 + 2] = fvB.z;
    sbB[3 + 4 * q0 + 3] = fvB.w;
    if (t < 192) {                                    // rel: 3 floats x 64 rows
        int g = t / 3, q = t - g * 3;
        long long row = row0 + g;
        int b = (int)(row >> 17);
        int u = (int)(row & (NS * NN - 1));
        int s = u >> 5;
        int src = src_ws[row];
        int ctr = centers_ws[b * NS + s];
        sbuf[g * 67 + q] = pos[((size_t)b * NPTS + src) * 3 + q]
                         - pos[((size_t)b * NPTS + ctr) * 3 + q];
    }
    __syncthreads();
    // 64*67 = 4288 floats = 1072 float4, contiguous & 16B-aligned per block.
    // Output is write-once, never re-read on device -> nontemporal (keep L3 for feat).
    f32x4* ob = (f32x4*)(out + (size_t)row0 * 67);
    const f32x4* sv = (const f32x4*)sbuf;
    __builtin_nontemporal_store(sv[t], &ob[t]);
    __builtin_nontemporal_store(sv[t + 512], &ob[t + 512]);
    if (t < 48) __builtin_nontemporal_store(sv[t + 1024], &ob[t + 1024]);
}

extern "C" void kernel_launch(void* const* d_in, const int* in_sizes, int n_in,
                              void* d_out, int out_size, void* d_ws, size_t ws_size,
                              hipStream_t stream) {
    (void)in_sizes; (void)n_in; (void)out_size; (void)ws_size;
    const float* pos = (const float*)d_in[0];
    const float* feat = (const float*)d_in[1];
    float* out = (float*)d_out;

    // ---- host-side JAX key-chain (threefry partitionable mode) ----
    RngKeys keys;
    for (int b = 0; b < NB; b++) {
        uint32_t rk0, rk1, kc0, kc1, kn0, kn1;
        tf2x32(0u, 42u, 0u, (uint32_t)b, rk0, rk1);
        tf2x32(rk0, rk1, 0u, 0u, kc0, kc1);
        tf2x32(rk0, rk1, 0u, 1u, kn0, kn1);
        tf2x32(kc0, kc1, 0u, 1u, keys.c0[b], keys.c1[b]);
        tf2x32(kn0, kn1, 0u, 1u, keys.n0[b], keys.n1[b]);
    }

    // ---- workspace layout (~26.5 MB) ----
    int* tab_key    = (int*)d_ws;                      // NB*TSLOTS (16B aligned)
    int* cnt        = tab_key + (size_t)NB * TSLOTS;   // NB*TSLOTS
    int* cursor     = cnt + (size_t)NB * TSLOTS;       // NB*TSLOTS
    int* bctr       = cursor + (size_t)NB * TSLOTS;    // NB
    int* slotOf     = bctr + NB;                       // NB*NPTS
    int* listA      = slotOf + (size_t)NB * NPTS;      // NB*NPTS
    int* listB      = listA + (size_t)NB * NPTS;       // NB*NPTS
    int* centers_ws = listB + (size_t)NB * NPTS;       // NB*NS
    int* src_ws     = centers_ws + (size_t)NB * NS;    // NB*NS*NN

    k_zero   <<<(NB * TSLOTS / 4) / 256, 256, 0, stream>>>((int4*)tab_key, (int4*)cnt,
                                                           bctr, (float4*)(out + OUT_CF));
    k_insert <<<(NB * NPTS) / 256, 256, 0, stream>>>(pos, tab_key, cnt, slotOf);
    k_starts <<<(NB * TSLOTS) / 256, 256, 0, stream>>>(cnt, cursor, bctr);
    k_scatter<<<(NB * NPTS) / 256, 256, 0, stream>>>(slotOf, cursor, listA);
    k_rank   <<<(NB * NPTS) / 256, 256, 0, stream>>>(slotOf, cnt, cursor, listA, listB);
    k_sel    <<<(NB * NS) / 8, 256, 0, stream>>>(keys, slotOf, tab_key, cnt, cursor,
                                                 listB, centers_ws, src_ws,
                                                 out + OUT_CTR, out + OUT_CF,
                                                 out + OUT_SRC, out + OUT_SF);
    k_gather <<<(NB * NS * NN) / 64, 512, 0, stream>>>(pos, feat, centers_ws, src_ws, out);
}

// Round 15
// 362.505 us; speedup vs baseline: 1.9044x; 1.0188x over previous
//
#include <hip/hip_runtime.h>
#include <stdint.h>

#define NB 8
#define NPTS 100000
#define NS 4096
#define NN 32
#define NCH 64
#define TLG 17
#define TSLOTS (1 << TLG)          // 131072 hash slots per batch
#define TMASK (TSLOTS - 1)

// d_out float layout (element offsets)
#define OUT_MAIN 0ull                          // [8,4096,32,67]
#define OUT_SRC  70254592ull                   // [8,4096,32]
#define OUT_CTR  71303168ull                   // [8,4096]
#define OUT_CF   71335936ull                   // [8,100000]
#define OUT_SF   72135936ull                   // [8,100000]

typedef float f32x4 __attribute__((ext_vector_type(4)));

__host__ __device__ static inline uint32_t rotl32(uint32_t v, int d) {
    return (v << d) | (v >> (32 - d));
}

// JAX threefry2x32 (5 groups of 4 rounds), exact.
__host__ __device__ static inline void tf2x32(uint32_t k0, uint32_t k1,
                                              uint32_t x0, uint32_t x1,
                                              uint32_t& o0, uint32_t& o1) {
    uint32_t ks2 = k0 ^ k1 ^ 0x1BD11BDAu;
    x0 += k0; x1 += k1;
    x0 += x1; x1 = rotl32(x1, 13); x1 ^= x0;
    x0 += x1; x1 = rotl32(x1, 15); x1 ^= x0;
    x0 += x1; x1 = rotl32(x1, 26); x1 ^= x0;
    x0 += x1; x1 = rotl32(x1, 6);  x1 ^= x0;
    x0 += k1; x1 += ks2 + 1u;
    x0 += x1; x1 = rotl32(x1, 17); x1 ^= x0;
    x0 += x1; x1 = rotl32(x1, 29); x1 ^= x0;
    x0 += x1; x1 = rotl32(x1, 16); x1 ^= x0;
    x0 += x1; x1 = rotl32(x1, 24); x1 ^= x0;
    x0 += ks2; x1 += k0 + 2u;
    x0 += x1; x1 = rotl32(x1, 13); x1 ^= x0;
    x0 += x1; x1 = rotl32(x1, 15); x1 ^= x0;
    x0 += x1; x1 = rotl32(x1, 26); x1 ^= x0;
    x0 += x1; x1 = rotl32(x1, 6);  x1 ^= x0;
    x0 += k0; x1 += k1 + 3u;
    x0 += x1; x1 = rotl32(x1, 17); x1 ^= x0;
    x0 += x1; x1 = rotl32(x1, 29); x1 ^= x0;
    x0 += x1; x1 = rotl32(x1, 16); x1 ^= x0;
    x0 += x1; x1 = rotl32(x1, 24); x1 ^= x0;
    x0 += k1; x1 += ks2 + 4u;
    x0 += x1; x1 = rotl32(x1, 13); x1 ^= x0;
    x0 += x1; x1 = rotl32(x1, 15); x1 ^= x0;
    x0 += x1; x1 = rotl32(x1, 26); x1 ^= x0;
    x0 += x1; x1 = rotl32(x1, 6);  x1 ^= x0;
    x0 += ks2; x1 += k0 + 5u;
    o0 = x0; o1 = x1;
}

struct RngKeys {
    uint32_t c0[NB], c1[NB];   // partitionable k2 keys: centers
    uint32_t n0[NB], n1[NB];   // partitionable k2 keys: neighbor draws
};

// partitionable random_bits(key, 32, ...): element u -> o0^o1, counter (0,u)
__device__ static inline uint32_t pbits32(uint32_t k0, uint32_t k1, uint32_t u) {
    uint32_t o0, o1;
    tf2x32(k0, k1, 0u, u, o0, o1);
    return o0 ^ o1;
}

// packed voxel key == reference hash: (vx+512)<<20 | (vy+512)<<10 | (vz+512)
__device__ static inline int voxhash(const float* __restrict__ p) {
    int vx = (int)floorf(p[0] * 4.0f);
    int vy = (int)floorf(p[1] * 4.0f);
    int vz = (int)floorf(p[2] * 4.0f);
    return ((vx + 512) << 20) | ((vy + 512) << 10) | (vz + 512);
}

__device__ static inline int hslot(int hk) {
    return (int)(((uint32_t)hk * 2654435761u) >> (32 - TLG)) & TMASK;
}

// ---------------- P0: init tables + flag outputs -----------------
__global__ void k_zero(int* __restrict__ tab_key, int* __restrict__ tab_cnt,
                       int* __restrict__ bctr, float4* __restrict__ flags4) {
    int t = blockIdx.x * blockDim.x + threadIdx.x;   // exact: NB*TSLOTS
    tab_key[t] = -1;
    tab_cnt[t] = 0;
    if (t < (2 * NB * NPTS) / 4) flags4[t] = make_float4(0.f, 0.f, 0.f, 0.f);
    if (t < NB) bctr[t] = 0;
}

// ---------------- P1: insert + count (+ remember slot per point) -----------
__global__ void k_insert(const float* __restrict__ pos,
                         int* __restrict__ tab_key, int* __restrict__ tab_cnt,
                         int* __restrict__ slotOf) {
    int t = blockIdx.x * blockDim.x + threadIdx.x;   // exact: NB*NPTS
    int b = t / NPTS;
    int hk = voxhash(pos + (size_t)t * 3);
    int base = b << TLG;
    int slot = hslot(hk);
    while (true) {
        int prev = atomicCAS(&tab_key[base + slot], -1, hk);
        if (prev == -1 || prev == hk) break;
        slot = (slot + 1) & TMASK;
    }
    slotOf[t] = slot;
    atomicAdd(&tab_cnt[base + slot], 1);
}

// ---------------- P2: assign bucket starts (block scan, 1 atomic/block) ----
__global__ void k_starts(int* __restrict__ tab_cnt, int* __restrict__ tab_start,
                         int* __restrict__ bctr) {
    __shared__ int sdata[256];
    __shared__ int sbase;
    int t = blockIdx.x * blockDim.x + threadIdx.x;   // exact: NB*TSLOTS
    int tid = threadIdx.x;
    int b = t >> TLG;                                // uniform per block
    int c = tab_cnt[t];
    sdata[tid] = c;
    __syncthreads();
    for (int off = 1; off < 256; off <<= 1) {        // Hillis-Steele inclusive
        int x = (tid >= off) ? sdata[tid - off] : 0;
        __syncthreads();
        sdata[tid] += x;
        __syncthreads();
    }
    if (tid == 255) sbase = atomicAdd(&bctr[b], sdata[255]);
    __syncthreads();
    if (c > 0) {
        tab_start[t] = sbase + sdata[tid] - c;       // exclusive prefix
        tab_cnt[t] = 0;                              // becomes fill counter
    }
}

// ---------------- P3: scatter arrival order -----------------
__global__ void k_scatter(const int* __restrict__ slotOf, int* __restrict__ tab_cnt,
                          const int* __restrict__ tab_start, int* __restrict__ listA) {
    int t = blockIdx.x * blockDim.x + threadIdx.x;   // exact: NB*NPTS
    int b = t / NPTS, i = t - b * NPTS;
    int slot = (b << TLG) + slotOf[t];
    int a = atomicAdd(&tab_cnt[slot], 1);            // restores cnt as side effect
    listA[(size_t)b * NPTS + tab_start[slot] + a] = i;
}

// ---------------- P4: rank within bucket -> index-sorted lists ------------
__global__ void k_rank(const int* __restrict__ slotOf,
                       const int* __restrict__ tab_cnt, const int* __restrict__ tab_start,
                       const int* __restrict__ listA, int* __restrict__ listB) {
    int t = blockIdx.x * blockDim.x + threadIdx.x;   // exact: NB*NPTS
    int b = t / NPTS, i = t - b * NPTS;
    int slot = (b << TLG) + slotOf[t];
    int s0 = tab_start[slot];
    int c = tab_cnt[slot];
    const int* L = listA + (size_t)b * NPTS + s0;
    int rank = 0;
    for (int k = 0; k < c; k++) rank += (L[k] < i) ? 1 : 0;
    listB[(size_t)b * NPTS + s0 + rank] = i;
}

// ------- P5: centers + 27-bin lookup + cumsum + selection (fully fused) ----
// 32 threads per sample: lanes 0..26 probe bins into LDS, all 32 select.
__global__ void k_sel(RngKeys keys, const float* __restrict__ pos,
                      const int* __restrict__ tab_key, const int* __restrict__ tab_cnt,
                      const int* __restrict__ tab_start, const int* __restrict__ listB,
                      int* __restrict__ centers_ws, int* __restrict__ src_ws,
                      float* __restrict__ out_ctr, float* __restrict__ out_cf,
                      float* __restrict__ out_src, float* __restrict__ out_sf) {
    __shared__ int scnt[8][27];
    __shared__ int slo[8][27];
    int tid = threadIdx.x;                           // 256 threads = 8 samples
    int g = tid >> 5, n = tid & 31;
    int bs = blockIdx.x * 8 + g;                     // exact: NB*NS/8 blocks
    int b = bs >> 12, s = bs & (NS - 1);
    uint32_t lower_c = pbits32(keys.c0[b], keys.c1[b], (uint32_t)s);
    int c = (int)(lower_c % 100000u);                // randint multiplier==0 path
    const float* p = pos + ((size_t)b * NPTS + c) * 3;
    int chk = voxhash(p);                            // same 12B for 32 lanes -> L1
    if (n < 27) {
        // neighbor voxel key by integer offset (coords never at the ±512 edge)
        int hk = chk + ((n / 9) - 1) * (1 << 20)
                     + (((n / 3) % 3) - 1) * (1 << 10)
                     + ((n % 3) - 1);
        int base = b << TLG;
        int slot = hslot(hk);
        int lo = 0, cnt = 0;
        while (true) {
            int k = tab_key[base + slot];
            if (k == hk) { lo = tab_start[base + slot]; cnt = tab_cnt[base + slot]; break; }
            if (k == -1) break;
            slot = (slot + 1) & TMASK;
        }
        scnt[g][n] = cnt;
        slo[g][n] = lo;
    }
    if (n == 0) {
        centers_ws[bs] = c;
        out_ctr[bs] = (float)c;
        out_cf[(size_t)b * NPTS + c] = 1.0f;
    }
    __syncthreads();
    uint32_t lower = pbits32(keys.n0[b], keys.n1[b], (uint32_t)(s * NN + n));
    int total = 0;
    #pragma unroll
    for (int i = 0; i < 27; i++) total += scnt[g][i];
    int r = (int)(lower & 0x3FFFFFFFu) % total;      // span=2^30 -> multiplier==0 path
    int slot = 0, prev = 0, acc = 0;
    #pragma unroll
    for (int i = 0; i < 27; i++) {
        acc += scnt[g][i];
        if (r >= acc) { slot = i + 1; prev = acc; }
    }
    int pos_in = slo[g][slot] + (r - prev);
    int src = listB[(size_t)b * NPTS + pos_in];
    int oi = bs * NN + n;
    src_ws[oi] = src;
    out_src[oi] = (float)src;
    out_sf[(size_t)b * NPTS + src] = 1.0f;
}

// ---- P6: output gather: 64 rows/block, 2 independent feat loads/thread ----
__global__ void k_gather(const float* __restrict__ pos, const float* __restrict__ feat,
                         const int* __restrict__ centers_ws, const int* __restrict__ src_ws,
                         float* __restrict__ out) {
    __shared__ float sbuf[64 * 67];                   // 17152 B
    int t = threadIdx.x;                              // 512 threads
    long long row0 = (long long)blockIdx.x * 64;      // exact: NB*NS*NN rows
    // two feat-quarter slots per thread -> 2 loads in flight (MLP)
    int g0 = t >> 4,          q0 = t & 15;
    int g1 = (t + 512) >> 4,  q1 = t & 15;            // (t+512)&15 == t&15
    long long rowA = row0 + g0, rowB = row0 + g1;
    int bA = (int)(rowA >> 17), bB = (int)(rowB >> 17);
    int srcA = src_ws[rowA];
    int srcB = src_ws[rowB];
    const float4 fvA = *(const float4*)(feat + ((size_t)bA * NPTS + srcA) * NCH + 4 * q0);
    const float4 fvB = *(const float4*)(feat + ((size_t)bB * NPTS + srcB) * NCH + 4 * q1);
    float* sbA = sbuf + g0 * 67;
    sbA[3 + 4 * q0 + 0] = fvA.x;
    sbA[3 + 4 * q0 + 1] = fvA.y;
    sbA[3 + 4 * q0 + 2] = fvA.z;
    sbA[3 + 4 * q0 + 3] = fvA.w;
    float* sbB = sbuf + g1 * 67;
    sbB[3 + 4 * q1 + 0] = fvB.x;
    sbB[3 + 4 * q1 + 1] = fvB.y;
    sbB[3 + 4 * q1 + 2] = fvB.z;
    sbB[3 + 4 * q1 + 3] = fvB.w;
    if (t < 192) {                                    // rel: 3 floats x 64 rows
        int g = t / 3, q = t - g * 3;
        long long row = row0 + g;
        int b = (int)(row >> 17);
        int u = (int)(row & (NS * NN - 1));
        int s = u >> 5;
        int src = src_ws[row];
        int ctr = centers_ws[b * NS + s];
        sbuf[g * 67 + q] = pos[((size_t)b * NPTS + src) * 3 + q]
                         - pos[((size_t)b * NPTS + ctr) * 3 + q];
    }
    __syncthreads();
    // 64*67 = 4288 floats = 1072 float4, contiguous & 16B-aligned per block.
    // Output is write-once, never re-read on device -> nontemporal (keep L3 for feat).
    f32x4* ob = (f32x4*)(out + (size_t)row0 * 67);
    const f32x4* sv = (const f32x4*)sbuf;
    __builtin_nontemporal_store(sv[t], &ob[t]);
    __builtin_nontemporal_store(sv[t + 512], &ob[t + 512]);
    if (t < 48) __builtin_nontemporal_store(sv[t + 1024], &ob[t + 1024]);
}

extern "C" void kernel_launch(void* const* d_in, const int* in_sizes, int n_in,
                              void* d_out, int out_size, void* d_ws, size_t ws_size,
                              hipStream_t stream) {
    (void)in_sizes; (void)n_in; (void)out_size; (void)ws_size;
    const float* pos = (const float*)d_in[0];
    const float* feat = (const float*)d_in[1];
    float* out = (float*)d_out;

    // ---- host-side JAX key-chain (threefry partitionable mode) ----
    RngKeys keys;
    for (int b = 0; b < NB; b++) {
        uint32_t rk0, rk1, kc0, kc1, kn0, kn1;
        tf2x32(0u, 42u, 0u, (uint32_t)b, rk0, rk1);
        tf2x32(rk0, rk1, 0u, 0u, kc0, kc1);
        tf2x32(rk0, rk1, 0u, 1u, kn0, kn1);
        tf2x32(kc0, kc1, 0u, 1u, keys.c0[b], keys.c1[b]);
        tf2x32(kn0, kn1, 0u, 1u, keys.n0[b], keys.n1[b]);
    }

    // ---- workspace layout (~26.5 MB) ----
    int* tab_key    = (int*)d_ws;                      // NB*TSLOTS
    int* tab_cnt    = tab_key + (size_t)NB * TSLOTS;   // NB*TSLOTS
    int* tab_start  = tab_cnt + (size_t)NB * TSLOTS;   // NB*TSLOTS
    int* bctr       = tab_start + (size_t)NB * TSLOTS; // NB
    int* slotOf     = bctr + NB;                       // NB*NPTS
    int* listA      = slotOf + (size_t)NB * NPTS;      // NB*NPTS
    int* listB      = listA + (size_t)NB * NPTS;       // NB*NPTS
    int* centers_ws = listB + (size_t)NB * NPTS;       // NB*NS
    int* src_ws     = centers_ws + (size_t)NB * NS;    // NB*NS*NN

    k_zero   <<<(NB * TSLOTS) / 256, 256, 0, stream>>>(tab_key, tab_cnt, bctr,
                                                       (float4*)(out + OUT_CF));
    k_insert <<<(NB * NPTS) / 256, 256, 0, stream>>>(pos, tab_key, tab_cnt, slotOf);
    k_starts <<<(NB * TSLOTS) / 256, 256, 0, stream>>>(tab_cnt, tab_start, bctr);
    k_scatter<<<(NB * NPTS) / 256, 256, 0, stream>>>(slotOf, tab_cnt, tab_start, listA);
    k_rank   <<<(NB * NPTS) / 256, 256, 0, stream>>>(slotOf, tab_cnt, tab_start,
                                                     listA, listB);
    k_sel    <<<(NB * NS) / 8, 256, 0, stream>>>(keys, pos, tab_key, tab_cnt, tab_start,
                                                 listB, centers_ws, src_ws,
                                                 out + OUT_CTR, out + OUT_CF,
                                                 out + OUT_SRC, out + OUT_SF);
    k_gather <<<(NB * NS * NN) / 64, 512, 0, stream>>>(pos, feat, centers_ws, src_ws, out);
}